// Round 2
// baseline (43783.606 us; speedup 1.0000x reference)
//
#include <hip/hip_runtime.h>

typedef float f32x4 __attribute__((ext_vector_type(4)));
typedef __bf16 bf16x8 __attribute__((ext_vector_type(8)));
typedef unsigned short u16;

#define OUTC 4864
#define OUTT ((size_t)63 * OUTC)
#define NBLK 512
#define GSTR (NBLK * 256)

__device__ __forceinline__ u16 f2bf(float f) {
    unsigned u = __float_as_uint(f);
    u += 0x7FFFu + ((u >> 16) & 1u);
    return (u16)(u >> 16);
}
__device__ __forceinline__ float bf2f(u16 h) { return __uint_as_float((unsigned)h << 16); }
__device__ __forceinline__ float fexp(float x) { return __expf(x); }
__device__ __forceinline__ float eluf(float x) { return x > 0.f ? x : fexp(x) - 1.f; }
__device__ __forceinline__ float splus(float x) { return x > 15.f ? x : __logf(1.f + fexp(x)); }
__device__ __forceinline__ float sigm(float x) { return 1.f / (1.f + fexp(-x)); }
__device__ __forceinline__ float tanhfast(float x) { return 2.f / (1.f + fexp(-2.f * x)) - 1.f; }
__device__ __forceinline__ int swz(int row, int cb) { return row * 128 + (cb ^ ((row & 7) << 4)); }

// -------- grid barrier (512 blocks co-resident by launch_bounds(256,2)) --------
__device__ __forceinline__ void gbar(unsigned* bar) {
    __threadfence();               // agent-scope release: L2 writeback (cross-XCD)
    __syncthreads();
    if (threadIdx.x == 0) {
        unsigned old = __hip_atomic_fetch_add(bar, 1u, __ATOMIC_ACQ_REL, __HIP_MEMORY_SCOPE_AGENT);
        unsigned target = (old / (unsigned)NBLK + 1u) * (unsigned)NBLK;
        int guard = 0;
        while (__hip_atomic_load(bar, __ATOMIC_RELAXED, __HIP_MEMORY_SCOPE_AGENT) < target) {
            __builtin_amdgcn_s_sleep(2);
            if (++guard > (1 << 20)) break;   // watchdog: avoid infinite hang
        }
    }
    __syncthreads();
    __threadfence();               // agent-scope acquire: invalidate local caches
}

// -------- generic NT-tile 64-row MFMA GEMM: C[m][n0+j*nstr+c] += A[m][k]*Bt[n][k] --------
template <int NT, class FA, class FE>
__device__ __forceinline__ void gemmN(char* As, FA fa, const u16* __restrict__ Bt,
                                      int ldb, int n0, int nstr, int K, int m0, FE fe) {
    char* Bs = As + 8192;
    const int tid = threadIdx.x;
    const int lane = tid & 63;
    const int w = tid >> 6;
    const int wr = (w >> 1) * 32, wc = (w & 1) * 32;
    f32x4 acc[NT][4];
    f32x4 zf = {0.f, 0.f, 0.f, 0.f};
#pragma unroll
    for (int j = 0; j < NT; j++)
#pragma unroll
        for (int q = 0; q < 4; q++) acc[j][q] = zf;
    const int r0 = tid >> 3;
    const int ke = (tid & 7) * 8;
    const int cb = (tid & 7) * 16;
    uint4 av0 = fa(m0 + r0, ke);
    uint4 av1 = fa(m0 + r0 + 32, ke);
    uint4 bv[NT][2];
#pragma unroll
    for (int j = 0; j < NT; j++) {
        bv[j][0] = *(const uint4*)(Bt + (size_t)(n0 + j * nstr + r0) * ldb + ke);
        bv[j][1] = *(const uint4*)(Bt + (size_t)(n0 + j * nstr + r0 + 32) * ldb + ke);
    }
    for (int k0 = 0; k0 < K; k0 += 64) {
        __syncthreads();
        *(uint4*)(As + swz(r0, cb)) = av0;
        *(uint4*)(As + swz(r0 + 32, cb)) = av1;
#pragma unroll
        for (int j = 0; j < NT; j++) {
            char* B = Bs + j * 8192;
            *(uint4*)(B + swz(r0, cb)) = bv[j][0];
            *(uint4*)(B + swz(r0 + 32, cb)) = bv[j][1];
        }
        __syncthreads();
        if (k0 + 64 < K) {          // prefetch next k-slice: overlaps with MFMA below
            int k1 = k0 + 64 + ke;
            av0 = fa(m0 + r0, k1);
            av1 = fa(m0 + r0 + 32, k1);
#pragma unroll
            for (int j = 0; j < NT; j++) {
                bv[j][0] = *(const uint4*)(Bt + (size_t)(n0 + j * nstr + r0) * ldb + k1);
                bv[j][1] = *(const uint4*)(Bt + (size_t)(n0 + j * nstr + r0 + 32) * ldb + k1);
            }
        }
#pragma unroll
        for (int kk = 0; kk < 64; kk += 32) {
            const int fcb = kk * 2 + (lane >> 4) * 16;
            bf16x8 a0 = *(const bf16x8*)(As + swz(wr + (lane & 15), fcb));
            bf16x8 a1 = *(const bf16x8*)(As + swz(wr + 16 + (lane & 15), fcb));
#pragma unroll
            for (int j = 0; j < NT; j++) {
                char* B = Bs + j * 8192;
                bf16x8 b0 = *(const bf16x8*)(B + swz(wc + (lane & 15), fcb));
                bf16x8 b1 = *(const bf16x8*)(B + swz(wc + 16 + (lane & 15), fcb));
                acc[j][0] = __builtin_amdgcn_mfma_f32_16x16x32_bf16(a0, b0, acc[j][0], 0, 0, 0);
                acc[j][1] = __builtin_amdgcn_mfma_f32_16x16x32_bf16(a0, b1, acc[j][1], 0, 0, 0);
                acc[j][2] = __builtin_amdgcn_mfma_f32_16x16x32_bf16(a1, b0, acc[j][2], 0, 0, 0);
                acc[j][3] = __builtin_amdgcn_mfma_f32_16x16x32_bf16(a1, b1, acc[j][3], 0, 0, 0);
            }
        }
    }
    const int er = (lane >> 4) * 4, ec = lane & 15;
#pragma unroll
    for (int q = 0; q < 4; q++) {
        int rr = m0 + wr + (q >> 1) * 16 + er;
        int cc = n0 + wc + (q & 1) * 16 + ec;
#pragma unroll
        for (int r = 0; r < 4; r++) {
            float vals[NT];
#pragma unroll
            for (int j = 0; j < NT; j++) vals[j] = acc[j][q][r];
            fe(rr + r, cc, vals);
        }
    }
}

// -------- prolog helpers --------
__device__ __forceinline__ void tpose(const float* __restrict__ in, u16* __restrict__ out,
                                      int R, int C, int Rpad, int total, int gtid) {
    for (int i = gtid; i < total; i += GSTR) {
        int r = i % Rpad;
        int bc = i / Rpad;
        int c = bc % C;
        int bb = bc / C;
        out[i] = (r < R) ? f2bf(in[((size_t)bb * R + r) * C + c]) : (u16)0;
    }
}
__device__ __forceinline__ void castb(const float* __restrict__ in, u16* __restrict__ out,
                                      int total, int gtid) {
    for (int i = gtid; i < total; i += GSTR) out[i] = f2bf(in[i]);
}

struct Args {
    const float *obs, *action, *nonterms, *init_deter, *init_stoch, *noise_p, *noise_q;
    const float *W_embed, *b_embed, *W_ens, *b_ens, *W_ih, *W_hh, *b_ih, *b_hh;
    const float *Wp1, *bp1, *Wp2, *bp2, *Wq1, *bq1, *Wq2, *bq2;
    float* out;
    u16 *Wembed_t, *Wih_b, *Whh_b, *Wens_t, *Wp1_t, *Wp2_t, *Wq1d_t, *Wq1o_t, *Wq2_t;
    u16 *OBSC, *x_embed, *h_nt, *sa, *deter_b;
    float *deter, *gi, *gh, *hp0, *hp1, *hq0, *hq1;
    unsigned* bar;
};

__global__ void __launch_bounds__(256, 2) rssm_persist(Args a) {
    __shared__ char sm[40960];
    const int vb = blockIdx.x;
    const int tid = threadIdx.x;
    const int gtid = vb * 256 + tid;

    // ===== P0a: weight prep + initial state =====
    tpose(a.W_embed, a.Wembed_t, 288, 1024, 320, 1024 * 320, gtid);
    castb(a.W_ih, a.Wih_b, 3072 * 1024, gtid);
    castb(a.W_hh, a.Whh_b, 3072 * 1024, gtid);
    tpose(a.W_ens, a.Wens_t, 1024, 256, 1024, 5 * 256 * 1024, gtid);
    tpose(a.Wp1, a.Wp1_t, 1024, 1024, 1024, 1024 * 1024, gtid);
    tpose(a.Wp2, a.Wp2_t, 1024, 512, 1024, 512 * 1024, gtid);
    tpose(a.Wq1, a.Wq1d_t, 1024, 1024, 1024, 1024 * 1024, gtid);
    tpose(a.Wq1 + 1024 * 1024, a.Wq1o_t, 1024, 1024, 1024, 1024 * 1024, gtid);
    tpose(a.Wq2, a.Wq2_t, 1024, 512, 1024, 512 * 1024, gtid);
    for (int idx = gtid; idx < 262144; idx += GSTR) {
        int b = idx >> 10, d = idx & 1023;
        float nt0 = a.nonterms[b * 64];
        float dv = a.init_deter[idx];
        a.deter[idx] = dv;
        a.h_nt[idx] = f2bf(dv * nt0);
        if (d < 256) {
            a.x_embed[b * 320 + d] = f2bf(a.init_stoch[b * 256 + d] * nt0);
        } else if (d < 320) {
            int c = d - 256;
            a.x_embed[b * 320 + d] = (c < 32) ? f2bf(a.action[(size_t)b * 2048 + c] * nt0) : (u16)0;
        }
    }
    gbar(a.bar);

    // ===== P0b: OBSC[t,b,n] = obs[b,t,:] @ Wq1_obs  (all steps at once) =====
    for (int jid = vb; jid < 1008; jid += NBLK) {
        int rb = jid >> 2, cg = jid & 3;
        int m0 = rb * 64, n0 = cg * 256;
        auto fa = [&](int r, int k) {
            int tt = r >> 8, bb = r & 255;
            const float* p = a.obs + ((size_t)bb * 64 + tt) * 1024 + k;
            float4 f0 = *(const float4*)p, f1 = *(const float4*)(p + 4);
            union { u16 h[8]; uint4 q; } x;
            x.h[0] = f2bf(f0.x); x.h[1] = f2bf(f0.y); x.h[2] = f2bf(f0.z); x.h[3] = f2bf(f0.w);
            x.h[4] = f2bf(f1.x); x.h[5] = f2bf(f1.y); x.h[6] = f2bf(f1.z); x.h[7] = f2bf(f1.w);
            return x.q;
        };
        auto fe = [&](int r, int n, const float* v) {
#pragma unroll
            for (int j = 0; j < 4; j++) a.OBSC[(size_t)r * 1024 + n + j * 64] = f2bf(v[j]);
        };
        gemmN<4>(sm, fa, a.Wq1o_t, 1024, n0, 64, 1024, m0, fe);
    }
    gbar(a.bar);

    // ===== main rollout =====
    for (int t = 0; t < 63; ++t) {
        // ---- P1: sa = elu(x_embed @ W_embed + b) ----
        if (vb < 64) {
            int rb = vb >> 4, cb2 = vb & 15;
            int m0 = rb * 64, n0 = cb2 * 64;
            auto fa = [&](int r, int k) { return *(const uint4*)(a.x_embed + r * 320 + k); };
            auto fe = [&](int r, int n, const float* v) {
                a.sa[r * 1024 + n] = f2bf(eluf(v[0] + a.b_embed[n]));
            };
            gemmN<1>(sm, fa, a.Wembed_t, 320, n0, 0, 320, m0, fe);
        }
        gbar(a.bar);
        // ---- P2: gi = sa@Wih^T + bih ; gh = h_nt@Whh^T + bhh ----
        if (vb < 384) {
            int j = vb;
            bool isgh = j >= 192;
            if (isgh) j -= 192;
            int rb = j / 48, cb2 = j % 48;
            int m0 = rb * 64, n0 = cb2 * 64;
            const u16* A = isgh ? a.h_nt : a.sa;
            const u16* B = isgh ? a.Whh_b : a.Wih_b;
            const float* bi = isgh ? a.b_hh : a.b_ih;
            float* dst = isgh ? a.gh : a.gi;
            auto fa = [&](int r, int k) { return *(const uint4*)(A + r * 1024 + k); };
            auto fe = [&](int r, int n, const float* v) { dst[(size_t)r * 3072 + n] = v[0] + bi[n]; };
            gemmN<1>(sm, fa, B, 1024, n0, 0, 1024, m0, fe);
        }
        gbar(a.bar);
        // ---- P3: ensemble preds (writes out) + GRU ----
        if (vb < 80) {
            int rb = vb / 20, cb2 = vb % 20;
            int m0 = rb * 64, n0 = cb2 * 64;
            float* op = a.out + (size_t)t * OUTC + 3584;
            auto fa = [&](int r, int k) { return *(const uint4*)(a.sa + r * 1024 + k); };
            auto fe = [&](int r, int n, const float* v) { op[(size_t)r * OUTT + n] = v[0] + a.b_ens[n]; };
            gemmN<1>(sm, fa, a.Wens_t, 1024, n0, 0, 1024, m0, fe);
        } else {
            for (int idx = (vb - 80) * 256 + tid; idx < 262144; idx += 432 * 256) {
                int b = idx >> 10, d = idx & 1023;
                float nt = a.nonterms[b * 64 + t];
                float h = a.deter[idx] * nt;
                size_t gb = (size_t)b * 3072;
                float r = sigm(a.gi[gb + d] + a.gh[gb + d]);
                float z = sigm(a.gi[gb + 1024 + d] + a.gh[gb + 1024 + d]);
                float n = tanhfast(a.gi[gb + 2048 + d] + r * a.gh[gb + 2048 + d]);
                float dn = (1.f - z) * n + z * h;
                a.deter[idx] = dn;
                a.deter_b[idx] = f2bf(dn);
                float* ob = a.out + (size_t)b * OUTT + (size_t)t * OUTC;
                ob[768 + d] = dn;
                ob[2560 + d] = dn;
            }
        }
        gbar(a.bar);
        // ---- P4: hp/hq raw partials, split-K 2x512 ----
        if (vb < 256) {
            int j = vb;
            bool isq = j >= 128;
            j &= 127;
            int kh = j & 1;
            j >>= 1;
            int rb = j / 16, cb2 = j % 16;
            int m0 = rb * 64, n0 = cb2 * 64;
            const u16* B = (isq ? a.Wq1d_t : a.Wp1_t) + kh * 512;
            float* dst = isq ? (kh ? a.hq1 : a.hq0) : (kh ? a.hp1 : a.hp0);
            auto fa = [&](int r, int k) {
                return *(const uint4*)(a.deter_b + r * 1024 + kh * 512 + k);
            };
            auto fe = [&](int r, int n, const float* v) { dst[(size_t)r * 1024 + n] = v[0]; };
            gemmN<1>(sm, fa, B, 1024, n0, 0, 512, m0, fe);
        }
        gbar(a.bar);
        // ---- P5: p2/q2 GEMM + dist epilogue; h_nt & x_embed-act for t+1 ----
        if (vb < 32) {
            bool isq = vb >= 16;
            int j = vb & 15;
            int rb = j >> 2, cb2 = j & 3;
            int m0 = rb * 64, n0 = cb2 * 64;
            const float* h0 = isq ? a.hq0 : a.hp0;
            const float* h1 = isq ? a.hq1 : a.hp1;
            const float* bi1 = isq ? a.bq1 : a.bp1;
            const u16* B = isq ? a.Wq2_t : a.Wp2_t;
            const float* b2 = isq ? a.bq2 : a.bp2;
            const u16* ob16 = isq ? (a.OBSC + (size_t)t * 256 * 1024) : (const u16*)0;
            auto fa = [&](int r, int k) {
                const float* u = h0 + (size_t)r * 1024 + k;
                const float* w2 = h1 + (size_t)r * 1024 + k;
                float4 ua = *(const float4*)u, ub = *(const float4*)(u + 4);
                float4 va = *(const float4*)w2, vb2 = *(const float4*)(w2 + 4);
                float4 ba = *(const float4*)(bi1 + k), bb = *(const float4*)(bi1 + k + 4);
                float s[8] = {ua.x + va.x + ba.x, ua.y + va.y + ba.y,
                              ua.z + va.z + ba.z, ua.w + va.w + ba.w,
                              ub.x + vb2.x + bb.x, ub.y + vb2.y + bb.y,
                              ub.z + vb2.z + bb.z, ub.w + vb2.w + bb.w};
                union { u16 h[8]; uint4 q; } x;
                if (ob16) {
                    union { u16 h[8]; uint4 q; } ov;
                    ov.q = *(const uint4*)(ob16 + (size_t)r * 1024 + k);
#pragma unroll
                    for (int i = 0; i < 8; i++) s[i] += bf2f(ov.h[i]);
                }
#pragma unroll
                for (int i = 0; i < 8; i++) x.h[i] = f2bf(eluf(s[i]));
                return x.q;
            };
            const float* noise = isq ? a.noise_q : a.noise_p;
            int obase = isq ? 1792 : 0;
            auto fe = [&](int r, int s, const float* v) {
                float m = v[0] + b2[s];
                float praw = v[1] + b2[s + 256];
                float sd = splus(praw) + 0.1f;
                float eps = noise[(size_t)t * 65536 + r * 256 + s];
                float st = m + sd * eps;
                float* obp = a.out + (size_t)r * OUTT + (size_t)t * OUTC + obase;
                obp[s] = m;
                obp[256 + s] = sd;
                obp[512 + s] = st;
                if (isq) {
                    float ntn = a.nonterms[r * 64 + t + 1];
                    a.x_embed[r * 320 + s] = f2bf(st * ntn);
                }
            };
            gemmN<2>(sm, fa, B, 1024, n0, 256, 1024, m0, fe);
        } else if (vb < 96) {
            for (int idx = (vb - 32) * 256 + tid; idx < 262144; idx += 64 * 256) {
                int b = idx >> 10;
                float ntn = a.nonterms[b * 64 + t + 1];
                a.h_nt[idx] = f2bf(a.deter[idx] * ntn);
            }
        } else if (vb < 100) {
            for (int i = (vb - 96) * 256 + tid; i < 16384; i += 4 * 256) {
                int b = i >> 6, c = i & 63;
                float ntn = a.nonterms[b * 64 + t + 1];
                u16 v = 0;
                if (c < 32) v = f2bf(a.action[(size_t)b * 2048 + (size_t)(t + 1) * 32 + c] * ntn);
                a.x_embed[b * 320 + 256 + c] = v;
            }
        }
        gbar(a.bar);
    }
}

// ---------------- host ----------------
extern "C" void kernel_launch(void* const* d_in, const int* in_sizes, int n_in,
                              void* d_out, int out_size, void* d_ws, size_t ws_size,
                              hipStream_t stream) {
    Args a;
    a.obs = (const float*)d_in[1];
    a.action = (const float*)d_in[2];
    a.nonterms = (const float*)d_in[3];
    a.init_deter = (const float*)d_in[4];
    a.init_stoch = (const float*)d_in[5];
    a.noise_p = (const float*)d_in[6];
    a.noise_q = (const float*)d_in[7];
    a.W_embed = (const float*)d_in[8];
    a.b_embed = (const float*)d_in[9];
    a.W_ens = (const float*)d_in[10];
    a.b_ens = (const float*)d_in[11];
    a.W_ih = (const float*)d_in[12];
    a.W_hh = (const float*)d_in[13];
    a.b_ih = (const float*)d_in[14];
    a.b_hh = (const float*)d_in[15];
    a.Wp1 = (const float*)d_in[16];
    a.bp1 = (const float*)d_in[17];
    a.Wp2 = (const float*)d_in[18];
    a.bp2 = (const float*)d_in[19];
    a.Wq1 = (const float*)d_in[20];
    a.bq1 = (const float*)d_in[21];
    a.Wq2 = (const float*)d_in[22];
    a.bq2 = (const float*)d_in[23];
    a.out = (float*)d_out;

    char* ws = (char*)d_ws;
    size_t off = 0;
    auto alloc = [&](size_t bytes) {
        void* p = ws + off;
        off += (bytes + 255) & ~(size_t)255;
        return p;
    };
    a.Wembed_t = (u16*)alloc((size_t)1024 * 320 * 2);
    a.Wih_b = (u16*)alloc((size_t)3072 * 1024 * 2);
    a.Whh_b = (u16*)alloc((size_t)3072 * 1024 * 2);
    a.Wens_t = (u16*)alloc((size_t)1280 * 1024 * 2);
    a.Wp1_t = (u16*)alloc((size_t)1024 * 1024 * 2);
    a.Wp2_t = (u16*)alloc((size_t)512 * 1024 * 2);
    a.Wq1d_t = (u16*)alloc((size_t)1024 * 1024 * 2);
    a.Wq1o_t = (u16*)alloc((size_t)1024 * 1024 * 2);
    a.Wq2_t = (u16*)alloc((size_t)512 * 1024 * 2);
    a.OBSC = (u16*)alloc((size_t)16128 * 1024 * 2);
    a.x_embed = (u16*)alloc((size_t)256 * 320 * 2);
    a.h_nt = (u16*)alloc((size_t)256 * 1024 * 2);
    a.sa = (u16*)alloc((size_t)256 * 1024 * 2);
    a.deter_b = (u16*)alloc((size_t)256 * 1024 * 2);
    a.deter = (float*)alloc((size_t)256 * 1024 * 4);
    a.gi = (float*)alloc((size_t)256 * 3072 * 4);
    a.gh = (float*)alloc((size_t)256 * 3072 * 4);
    a.hp0 = (float*)alloc((size_t)256 * 1024 * 4);
    a.hp1 = (float*)alloc((size_t)256 * 1024 * 4);
    a.hq0 = (float*)alloc((size_t)256 * 1024 * 4);
    a.hq1 = (float*)alloc((size_t)256 * 1024 * 4);
    a.bar = (unsigned*)alloc(256);
    (void)ws_size;
    (void)in_sizes;
    (void)n_in;
    (void)out_size;

    hipMemsetAsync(a.bar, 0, 256, stream);
    rssm_persist<<<NBLK, 256, 0, stream>>>(a);
}

// Round 3
// 5470.720 us; speedup vs baseline: 8.0033x; 8.0033x over previous
//
#include <hip/hip_runtime.h>

typedef float f32x4 __attribute__((ext_vector_type(4)));
typedef __bf16 bf16x8 __attribute__((ext_vector_type(8)));
typedef unsigned short u16;

#define OUTC 4864
#define OUTT ((size_t)63 * OUTC)

__device__ __forceinline__ u16 f2bf(float f) {
    unsigned u = __float_as_uint(f);
    u += 0x7FFFu + ((u >> 16) & 1u);
    return (u16)(u >> 16);
}
__device__ __forceinline__ float bf2f(u16 h) { return __uint_as_float((unsigned)h << 16); }
__device__ __forceinline__ float fexp(float x) { return __expf(x); }
__device__ __forceinline__ float eluf(float x) { return x > 0.f ? x : fexp(x) - 1.f; }
__device__ __forceinline__ float splus(float x) { return x > 15.f ? x : __logf(1.f + fexp(x)); }
__device__ __forceinline__ float sigm(float x) { return 1.f / (1.f + fexp(-x)); }
__device__ __forceinline__ float tanhfast(float x) { return 2.f / (1.f + fexp(-2.f * x)) - 1.f; }
__device__ __forceinline__ int swz(int row, int cb) { return row * 128 + (cb ^ ((row & 7) << 4)); }

// -------- generic NT-tile 64-row MFMA GEMM: out col = n0 + j*nstr + c --------
template <int NT, class FA, class FE>
__device__ __forceinline__ void gemmN(char* As, FA fa, const u16* __restrict__ Bt,
                                      int ldb, int n0, int nstr, int K, int m0, FE fe) {
    char* Bs = As + 8192;
    const int tid = threadIdx.x;
    const int lane = tid & 63;
    const int w = tid >> 6;
    const int wr = (w >> 1) * 32, wc = (w & 1) * 32;
    f32x4 acc[NT][4];
    f32x4 zf = {0.f, 0.f, 0.f, 0.f};
#pragma unroll
    for (int j = 0; j < NT; j++)
#pragma unroll
        for (int q = 0; q < 4; q++) acc[j][q] = zf;
    const int r0 = tid >> 3;
    const int ke = (tid & 7) * 8;
    const int cb = (tid & 7) * 16;
    uint4 av0 = fa(m0 + r0, ke);
    uint4 av1 = fa(m0 + r0 + 32, ke);
    uint4 bv[NT][2];
#pragma unroll
    for (int j = 0; j < NT; j++) {
        bv[j][0] = *(const uint4*)(Bt + (size_t)(n0 + j * nstr + r0) * ldb + ke);
        bv[j][1] = *(const uint4*)(Bt + (size_t)(n0 + j * nstr + r0 + 32) * ldb + ke);
    }
    for (int k0 = 0; k0 < K; k0 += 64) {
        __syncthreads();
        *(uint4*)(As + swz(r0, cb)) = av0;
        *(uint4*)(As + swz(r0 + 32, cb)) = av1;
#pragma unroll
        for (int j = 0; j < NT; j++) {
            char* B = Bs + j * 8192;
            *(uint4*)(B + swz(r0, cb)) = bv[j][0];
            *(uint4*)(B + swz(r0 + 32, cb)) = bv[j][1];
        }
        __syncthreads();
        if (k0 + 64 < K) {
            int k1 = k0 + 64 + ke;
            av0 = fa(m0 + r0, k1);
            av1 = fa(m0 + r0 + 32, k1);
#pragma unroll
            for (int j = 0; j < NT; j++) {
                bv[j][0] = *(const uint4*)(Bt + (size_t)(n0 + j * nstr + r0) * ldb + k1);
                bv[j][1] = *(const uint4*)(Bt + (size_t)(n0 + j * nstr + r0 + 32) * ldb + k1);
            }
        }
#pragma unroll
        for (int kk = 0; kk < 64; kk += 32) {
            const int fcb = kk * 2 + (lane >> 4) * 16;
            bf16x8 a0 = *(const bf16x8*)(As + swz(wr + (lane & 15), fcb));
            bf16x8 a1 = *(const bf16x8*)(As + swz(wr + 16 + (lane & 15), fcb));
#pragma unroll
            for (int j = 0; j < NT; j++) {
                char* B = Bs + j * 8192;
                bf16x8 b0 = *(const bf16x8*)(B + swz(wc + (lane & 15), fcb));
                bf16x8 b1 = *(const bf16x8*)(B + swz(wc + 16 + (lane & 15), fcb));
                acc[j][0] = __builtin_amdgcn_mfma_f32_16x16x32_bf16(a0, b0, acc[j][0], 0, 0, 0);
                acc[j][1] = __builtin_amdgcn_mfma_f32_16x16x32_bf16(a0, b1, acc[j][1], 0, 0, 0);
                acc[j][2] = __builtin_amdgcn_mfma_f32_16x16x32_bf16(a1, b0, acc[j][2], 0, 0, 0);
                acc[j][3] = __builtin_amdgcn_mfma_f32_16x16x32_bf16(a1, b1, acc[j][3], 0, 0, 0);
            }
        }
    }
    const int er = (lane >> 4) * 4, ec = lane & 15;
#pragma unroll
    for (int q = 0; q < 4; q++) {
        int rr = m0 + wr + (q >> 1) * 16 + er;
        int cc = n0 + wc + (q & 1) * 16 + ec;
#pragma unroll
        for (int r = 0; r < 4; r++) {
            float vals[NT];
#pragma unroll
            for (int j = 0; j < NT; j++) vals[j] = acc[j][q][r];
            fe(rr + r, cc, vals);
        }
    }
}

// ---------------- weight prep ----------------
__global__ void __launch_bounds__(256) k_cast(const float* __restrict__ in,
                                              u16* __restrict__ out, int n) {
    int i = blockIdx.x * 256 + threadIdx.x;
    if (i < n) out[i] = f2bf(in[i]);
}

__global__ void __launch_bounds__(256) k_transpose(const float* __restrict__ in,
                                                   u16* __restrict__ out,
                                                   int R, int C, int Rpad, int total) {
    int i = blockIdx.x * 256 + threadIdx.x;
    if (i >= total) return;
    int r = i % Rpad;
    int bc = i / Rpad;
    int c = bc % C;
    int bb = bc / C;
    out[i] = (r < R) ? f2bf(in[((size_t)bb * R + r) * C + c]) : (u16)0;
}

// ---------------- init ----------------
__global__ void __launch_bounds__(256) k_init(const float* __restrict__ init_deter,
                                              const float* __restrict__ init_stoch,
                                              const float* __restrict__ action,
                                              const float* __restrict__ nonterms,
                                              float* __restrict__ deter,
                                              u16* __restrict__ h_nt,
                                              u16* __restrict__ x_embed) {
    int idx = blockIdx.x * 256 + threadIdx.x;  // 256*1024
    int b = idx >> 10, d = idx & 1023;
    float nt0 = nonterms[b * 64];
    float dv = init_deter[idx];
    deter[idx] = dv;
    h_nt[idx] = f2bf(dv * nt0);
    if (d < 256) {
        x_embed[b * 320 + d] = f2bf(init_stoch[b * 256 + d] * nt0);
    } else if (d < 320) {
        int c = d - 256;
        x_embed[b * 320 + d] = (c < 32) ? f2bf(action[(size_t)b * 2048 + c] * nt0) : (u16)0;
    }
}

// ---------------- OBSC precompute: [t*256+b][n] = obs[b,t,:] @ Wq1_obs ----------------
__global__ void __launch_bounds__(256) k_obsc(const float* __restrict__ obs,
                                              const u16* __restrict__ Wq1o_t,
                                              u16* __restrict__ OBSC) {
    __shared__ char sm[40960];
    int jid = blockIdx.x;           // 1008 = 252 * 4
    int rb = jid >> 2, cg = jid & 3;
    int m0 = rb * 64, n0 = cg * 256;
    auto fa = [&](int r, int k) {
        int tt = r >> 8, bb = r & 255;
        const float* p = obs + ((size_t)bb * 64 + tt) * 1024 + k;
        float4 f0 = *(const float4*)p, f1 = *(const float4*)(p + 4);
        union { u16 h[8]; uint4 q; } x;
        x.h[0] = f2bf(f0.x); x.h[1] = f2bf(f0.y); x.h[2] = f2bf(f0.z); x.h[3] = f2bf(f0.w);
        x.h[4] = f2bf(f1.x); x.h[5] = f2bf(f1.y); x.h[6] = f2bf(f1.z); x.h[7] = f2bf(f1.w);
        return x.q;
    };
    auto fe = [&](int r, int n, const float* v) {
#pragma unroll
        for (int j = 0; j < 4; j++) OBSC[(size_t)r * 1024 + n + j * 64] = f2bf(v[j]);
    };
    gemmN<4>(sm, fa, Wq1o_t, 1024, n0, 64, 1024, m0, fe);
}

// ---------------- per-step kernels ----------------
__global__ void __launch_bounds__(256) k_sa(const u16* __restrict__ xe,
                                            const u16* __restrict__ Wt,
                                            const float* __restrict__ bias,
                                            u16* __restrict__ sa) {
    __shared__ char sm[16384];
    int m0 = blockIdx.y * 64, n0 = blockIdx.x * 64;
    auto fa = [&](int r, int k) { return *(const uint4*)(xe + r * 320 + k); };
    auto fe = [&](int r, int n, const float* v) {
        sa[r * 1024 + n] = f2bf(eluf(v[0] + bias[n]));
    };
    gemmN<1>(sm, fa, Wt, 320, n0, 0, 320, m0, fe);
}

// generic M=256,N=3072,K=1024 fp32-out GEMM (gi and gh)
__global__ void __launch_bounds__(256) k_gemm3072(const u16* __restrict__ A,
                                                  const u16* __restrict__ B,
                                                  const float* __restrict__ bias,
                                                  float* __restrict__ dst) {
    __shared__ char sm[16384];
    int m0 = blockIdx.y * 64, n0 = blockIdx.x * 64;
    auto fa = [&](int r, int k) { return *(const uint4*)(A + r * 1024 + k); };
    auto fe = [&](int r, int n, const float* v) { dst[(size_t)r * 3072 + n] = v[0] + bias[n]; };
    gemmN<1>(sm, fa, B, 1024, n0, 0, 1024, m0, fe);
}

__global__ void __launch_bounds__(256) k_gru(const float* __restrict__ gi,
                                             const float* __restrict__ gh,
                                             float* __restrict__ deter,
                                             const float* __restrict__ nonterms, int t,
                                             u16* __restrict__ deter_hist,
                                             u16* __restrict__ h_nt,
                                             float* __restrict__ out) {
    int idx = blockIdx.x * 256 + threadIdx.x;
    int b = idx >> 10, d = idx & 1023;
    float nt = nonterms[b * 64 + t];
    float h = deter[idx] * nt;
    size_t gb = (size_t)b * 3072;
    float r = sigm(gi[gb + d] + gh[gb + d]);
    float z = sigm(gi[gb + 1024 + d] + gh[gb + 1024 + d]);
    float n = tanhfast(gi[gb + 2048 + d] + r * gh[gb + 2048 + d]);
    float dn = (1.f - z) * n + z * h;
    deter[idx] = dn;
    u16 db = f2bf(dn);
    deter_hist[(size_t)t * 262144 + idx] = db;
    h_nt[idx] = f2bf(dn * nonterms[b * 64 + t + 1]);
    float* ob = out + (size_t)b * OUTT + (size_t)t * OUTC;
    ob[768 + d] = dn;
    ob[2560 + d] = dn;
}

// 256 blocks: [0,192) gh(t+1) = h_nt @ Whh ; [192,256) HQ = elu(deter@Wq1d + OBSC + bq1)
__global__ void __launch_bounds__(256) k_step4(const u16* __restrict__ h_nt,
                                               const u16* __restrict__ Whh_b,
                                               const float* __restrict__ b_hh,
                                               float* __restrict__ gh,
                                               const u16* __restrict__ deter_hist,
                                               const u16* __restrict__ Wq1d_t,
                                               const float* __restrict__ bq1,
                                               const u16* __restrict__ OBSC,
                                               u16* __restrict__ HQ, int t) {
    __shared__ char sm[16384];
    int bid = blockIdx.x;
    if (bid < 192) {
        if (t >= 62) return;  // no step t+1
        int m0 = (bid / 48) * 64, n0 = (bid % 48) * 64;
        auto fa = [&](int r, int k) { return *(const uint4*)(h_nt + r * 1024 + k); };
        auto fe = [&](int r, int n, const float* v) { gh[(size_t)r * 3072 + n] = v[0] + b_hh[n]; };
        gemmN<1>(sm, fa, Whh_b, 1024, n0, 0, 1024, m0, fe);
    } else {
        int j = bid - 192;
        int m0 = (j / 16) * 64, n0 = (j % 16) * 64;
        const u16* A = deter_hist + (size_t)t * 262144;
        const u16* ob = OBSC + (size_t)t * 262144;
        auto fa = [&](int r, int k) { return *(const uint4*)(A + r * 1024 + k); };
        auto fe = [&](int r, int n, const float* v) {
            HQ[r * 1024 + n] = f2bf(eluf(v[0] + bq1[n] + bf2f(ob[r * 1024 + n])));
        };
        gemmN<1>(sm, fa, Wq1d_t, 1024, n0, 0, 1024, m0, fe);
    }
}

// 20 blocks: [0,16) q2 GEMM + post sampling + x_embed stoch; [16,20) x_embed action
__global__ void __launch_bounds__(256) k_q2dist(const u16* __restrict__ HQ,
                                                const u16* __restrict__ Wq2_t,
                                                const float* __restrict__ bq2,
                                                const float* __restrict__ noise_q,
                                                const float* __restrict__ nonterms,
                                                const float* __restrict__ action,
                                                float* __restrict__ out,
                                                u16* __restrict__ x_embed, int t) {
    __shared__ char sm[24576];
    int bid = blockIdx.x;
    if (bid < 16) {
        int m0 = (bid >> 2) * 64, n0 = (bid & 3) * 64;
        auto fa = [&](int r, int k) { return *(const uint4*)(HQ + r * 1024 + k); };
        auto fe = [&](int r, int s, const float* v) {
            float m = v[0] + bq2[s];
            float sd = splus(v[1] + bq2[s + 256]) + 0.1f;
            float eps = noise_q[(size_t)t * 65536 + r * 256 + s];
            float st = m + sd * eps;
            float* obp = out + (size_t)r * OUTT + (size_t)t * OUTC + 1792;
            obp[s] = m;
            obp[256 + s] = sd;
            obp[512 + s] = st;
            float ntn = nonterms[r * 64 + t + 1];
            x_embed[r * 320 + s] = f2bf(st * ntn);
        };
        gemmN<2>(sm, fa, Wq2_t, 1024, n0, 256, 1024, m0, fe);
    } else {
        for (int i = (bid - 16) * 256 + threadIdx.x; i < 16384; i += 1024) {
            int b = i >> 6, c = i & 63;
            float ntn = nonterms[b * 64 + t + 1];
            u16 v = 0;
            if (c < 32) v = f2bf(action[(size_t)b * 2048 + (size_t)(t + 1) * 32 + c] * ntn);
            x_embed[b * 320 + 256 + c] = v;
        }
    }
}

// ---------------- batched epilogues (M = 16128) ----------------
__global__ void __launch_bounds__(256) k_ens(const u16* __restrict__ sa_hist,
                                             const u16* __restrict__ Wens_t,
                                             const float* __restrict__ b_ens,
                                             float* __restrict__ out) {
    __shared__ char sm[40960];
    int m0 = blockIdx.y * 64, n0 = blockIdx.x * 256;
    auto fa = [&](int r, int k) { return *(const uint4*)(sa_hist + (size_t)r * 1024 + k); };
    auto fe = [&](int r, int cc, const float* v) {
        int tt = r >> 8, b = r & 255;
        float* op = out + (size_t)b * OUTT + (size_t)tt * OUTC + 3584;
#pragma unroll
        for (int j = 0; j < 4; j++) {
            int n = cc + j * 64;
            op[n] = v[j] + b_ens[n];
        }
    };
    gemmN<4>(sm, fa, Wens_t, 1024, n0, 64, 1024, m0, fe);
}

__global__ void __launch_bounds__(256) k_hp(const u16* __restrict__ deter_hist,
                                            const u16* __restrict__ Wp1_t,
                                            const float* __restrict__ bp1,
                                            u16* __restrict__ HP) {
    __shared__ char sm[40960];
    int m0 = blockIdx.y * 64, n0 = blockIdx.x * 256;
    auto fa = [&](int r, int k) { return *(const uint4*)(deter_hist + (size_t)r * 1024 + k); };
    auto fe = [&](int r, int cc, const float* v) {
#pragma unroll
        for (int j = 0; j < 4; j++) {
            int n = cc + j * 64;
            HP[(size_t)r * 1024 + n] = f2bf(eluf(v[j] + bp1[n]));
        }
    };
    gemmN<4>(sm, fa, Wp1_t, 1024, n0, 64, 1024, m0, fe);
}

__global__ void __launch_bounds__(256) k_p2(const u16* __restrict__ HP,
                                            const u16* __restrict__ Wp2_t,
                                            const float* __restrict__ bp2,
                                            const float* __restrict__ noise_p,
                                            float* __restrict__ out) {
    __shared__ char sm[24576];
    int m0 = blockIdx.y * 64, n0 = blockIdx.x * 64;
    auto fa = [&](int r, int k) { return *(const uint4*)(HP + (size_t)r * 1024 + k); };
    auto fe = [&](int r, int s, const float* v) {
        int tt = r >> 8, b = r & 255;
        float m = v[0] + bp2[s];
        float sd = splus(v[1] + bp2[s + 256]) + 0.1f;
        float eps = noise_p[(size_t)tt * 65536 + b * 256 + s];
        float st = m + sd * eps;
        float* obp = out + (size_t)b * OUTT + (size_t)tt * OUTC;
        obp[s] = m;
        obp[256 + s] = sd;
        obp[512 + s] = st;
    };
    gemmN<2>(sm, fa, Wp2_t, 1024, n0, 256, 1024, m0, fe);
}

// ---------------- host ----------------
extern "C" void kernel_launch(void* const* d_in, const int* in_sizes, int n_in,
                              void* d_out, int out_size, void* d_ws, size_t ws_size,
                              hipStream_t stream) {
    const float* obs = (const float*)d_in[1];
    const float* action = (const float*)d_in[2];
    const float* nonterms = (const float*)d_in[3];
    const float* init_deter = (const float*)d_in[4];
    const float* init_stoch = (const float*)d_in[5];
    const float* noise_p = (const float*)d_in[6];
    const float* noise_q = (const float*)d_in[7];
    const float* W_embed = (const float*)d_in[8];
    const float* b_embed = (const float*)d_in[9];
    const float* W_ens = (const float*)d_in[10];
    const float* b_ens = (const float*)d_in[11];
    const float* W_ih = (const float*)d_in[12];
    const float* W_hh = (const float*)d_in[13];
    const float* b_ih = (const float*)d_in[14];
    const float* b_hh = (const float*)d_in[15];
    const float* Wp1 = (const float*)d_in[16];
    const float* bp1 = (const float*)d_in[17];
    const float* Wp2 = (const float*)d_in[18];
    const float* bp2 = (const float*)d_in[19];
    const float* Wq1 = (const float*)d_in[20];
    const float* bq1 = (const float*)d_in[21];
    const float* Wq2 = (const float*)d_in[22];
    const float* bq2 = (const float*)d_in[23];
    float* out = (float*)d_out;

    char* ws = (char*)d_ws;
    size_t off = 0;
    auto alloc = [&](size_t bytes) {
        void* p = ws + off;
        off += (bytes + 255) & ~(size_t)255;
        return p;
    };
    u16* Wembed_t = (u16*)alloc((size_t)1024 * 320 * 2);
    u16* Wih_b = (u16*)alloc((size_t)3072 * 1024 * 2);
    u16* Whh_b = (u16*)alloc((size_t)3072 * 1024 * 2);
    u16* Wens_t = (u16*)alloc((size_t)1280 * 1024 * 2);
    u16* Wp1_t = (u16*)alloc((size_t)1024 * 1024 * 2);
    u16* Wp2_t = (u16*)alloc((size_t)512 * 1024 * 2);
    u16* Wq1d_t = (u16*)alloc((size_t)1024 * 1024 * 2);
    u16* Wq1o_t = (u16*)alloc((size_t)1024 * 1024 * 2);
    u16* Wq2_t = (u16*)alloc((size_t)512 * 1024 * 2);
    u16* OBSC = (u16*)alloc((size_t)16128 * 1024 * 2);  // reused as HP in epilogue
    u16* sa_hist = (u16*)alloc((size_t)16128 * 1024 * 2);
    u16* deter_hist = (u16*)alloc((size_t)16128 * 1024 * 2);
    u16* x_embed = (u16*)alloc((size_t)256 * 320 * 2);
    u16* h_nt = (u16*)alloc((size_t)256 * 1024 * 2);
    u16* HQ = (u16*)alloc((size_t)256 * 1024 * 2);
    float* deter = (float*)alloc((size_t)256 * 1024 * 4);
    float* gi = (float*)alloc((size_t)256 * 3072 * 4);
    float* gh = (float*)alloc((size_t)256 * 3072 * 4);
    (void)ws_size; (void)in_sizes; (void)n_in; (void)out_size;

    // ---- prolog: weight prep ----
    {
        int tot = 1024 * 320;
        k_transpose<<<(tot + 255) / 256, 256, 0, stream>>>(W_embed, Wembed_t, 288, 1024, 320, tot);
        int nc = 3072 * 1024;
        k_cast<<<(nc + 255) / 256, 256, 0, stream>>>(W_ih, Wih_b, nc);
        k_cast<<<(nc + 255) / 256, 256, 0, stream>>>(W_hh, Whh_b, nc);
        tot = 5 * 256 * 1024;
        k_transpose<<<(tot + 255) / 256, 256, 0, stream>>>(W_ens, Wens_t, 1024, 256, 1024, tot);
        tot = 1024 * 1024;
        k_transpose<<<(tot + 255) / 256, 256, 0, stream>>>(Wp1, Wp1_t, 1024, 1024, 1024, tot);
        tot = 512 * 1024;
        k_transpose<<<(tot + 255) / 256, 256, 0, stream>>>(Wp2, Wp2_t, 1024, 512, 1024, tot);
        tot = 1024 * 1024;
        k_transpose<<<(tot + 255) / 256, 256, 0, stream>>>(Wq1, Wq1d_t, 1024, 1024, 1024, tot);
        k_transpose<<<(tot + 255) / 256, 256, 0, stream>>>(Wq1 + 1024 * 1024, Wq1o_t, 1024, 1024, 1024, tot);
        tot = 512 * 1024;
        k_transpose<<<(tot + 255) / 256, 256, 0, stream>>>(Wq2, Wq2_t, 1024, 512, 1024, tot);
    }
    k_init<<<1024, 256, 0, stream>>>(init_deter, init_stoch, action, nonterms,
                                     deter, h_nt, x_embed);
    k_obsc<<<1008, 256, 0, stream>>>(obs, Wq1o_t, OBSC);
    // gh(0)
    k_gemm3072<<<dim3(48, 4), 256, 0, stream>>>(h_nt, Whh_b, b_hh, gh);

    // ---- rollout: 5 launches per step ----
    for (int t = 0; t < 63; t++) {
        u16* sa_t = sa_hist + (size_t)t * 262144;
        k_sa<<<dim3(16, 4), 256, 0, stream>>>(x_embed, Wembed_t, b_embed, sa_t);
        k_gemm3072<<<dim3(48, 4), 256, 0, stream>>>(sa_t, Wih_b, b_ih, gi);
        k_gru<<<1024, 256, 0, stream>>>(gi, gh, deter, nonterms, t, deter_hist, h_nt, out);
        k_step4<<<256, 256, 0, stream>>>(h_nt, Whh_b, b_hh, gh, deter_hist, Wq1d_t,
                                         bq1, OBSC, HQ, t);
        k_q2dist<<<20, 256, 0, stream>>>(HQ, Wq2_t, bq2, noise_q, nonterms, action,
                                         out, x_embed, t);
    }

    // ---- batched epilogues ----
    k_ens<<<dim3(5, 252), 256, 0, stream>>>(sa_hist, Wens_t, b_ens, out);
    u16* HP = OBSC;  // reuse (OBSC fully consumed)
    k_hp<<<dim3(4, 252), 256, 0, stream>>>(deter_hist, Wp1_t, bp1, HP);
    k_p2<<<dim3(4, 252), 256, 0, stream>>>(HP, Wp2_t, bp2, noise_p, out);
}